// Round 11
// baseline (675.760 us; speedup 1.0000x reference)
//
#include <hip/hip_runtime.h>

// Problem constants
#define NATOMS 4096
#define NTYPES 2
#define NA 2048
#define MAXNB 100
#define JN 200          // neighbors per atom
#define TFD 4
#define E0 25
#define E1 50
#define GD 100
#define M2D 16
#define DD 1600
#define FHD 240
#define INV200 (1.0f/200.0f)

// Output layout (floats): Etot@0 (1), Ei@1 (4096), F@4097 (12288), Virial@16385 (9)
#define OUT_EI 1
#define OUT_F 4097
#define OUT_V 16385

// Workspace layout (floats). Total ~17.0M floats = 68 MB.
#define WS_Q 0L                  // Q fp32 [2][2048][1600] (written by gemmQ)
#define WS_FW1NB 0L              // bf16 fw1Nb [2][256][256] aliases Q head; consumed by dh0g-gemm BEFORE gemmQ
#define WS_DRB 6553600L          // dr bf16 [2][2048][1600] (k1 -> mgemm fh0)
#define WS_U1B 6553600L          // bf16 u1 [4096][256] aliases drb head; written AFTER fh0-gemm consumed drb
#define WS_XA 9830400L           // 4096*400
#define WS_P 11468800L           // 4096*400 (g-major float4 [n][g][c])
#define WS_FH0 13107200L         // fp32 [4096][240]
#define WS_FH1 14090240L         // fp32 [4096][240]
#define WS_DH0GB 15073280L       // bf16 [2][2048][256] zero-padded K
#define WS_FH0B 15597568L        // bf16 [2][2048][256] zero-padded K
#define WS_FW0TB 16121856L       // bf16 [2][256][1600] (rows>=240 garbage-ok)
#define WS_FW0B 16531456L        // bf16 [2][1600][256] (cols>=240 zero)
#define WS_FW1TB 16941056L       // bf16 [2][256][256] (cols>=240 zero, rows>=240 garbage-ok)

// G(s) lookup table: 1-D function of s per type (temb const per type).
#define NK 1024
#define S_MIN (-8.0f)
#define S_H 0.015625f
#define S_INVH 64.0f
#define HCH 104                  // channels padded to 13*8 for fp16 table
__device__ float4 g_tab4[NTYPES * NK * GD];
__device__ float2 g_th1[NTYPES * NK * E1];
// fp16 table: [t][knot][ch][4] = (G_i, dG=G_{i+1}-G_i, dv_i, dv_{i+1})
__device__ _Float16 h_tab[NTYPES * NK * HCH * 4];

typedef __attribute__((ext_vector_type(8))) short bf16x8;
typedef __attribute__((ext_vector_type(4))) float f32x4;
typedef __attribute__((ext_vector_type(2))) _Float16 h16x2;

#if defined(__has_builtin)
#if __has_builtin(__builtin_amdgcn_fdot2)
#define HAVE_FDOT2 1
#endif
#endif
#ifdef HAVE_FDOT2
#define FDOT2(a, b, c) __builtin_amdgcn_fdot2((a), (b), (c), false)
#else
__device__ __forceinline__ float fdot2_sw(h16x2 a, h16x2 b, float c) {
    return fmaf((float)a[0], (float)b[0], fmaf((float)a[1], (float)b[1], c));
}
#define FDOT2(a, b, c) fdot2_sw((a), (b), (c))
#endif

__device__ __forceinline__ h16x2 as_h2(unsigned u) {
    union { unsigned u; h16x2 h; } v; v.u = u; return v.h;
}

__device__ __forceinline__ unsigned h2u(h16x2 h) {
    union { h16x2 h; unsigned u; } v; v.h = h; return v.u;
}

__device__ __forceinline__ float ftanh(float x) {
    float ax = fabsf(x);
    float e = __expf(-2.0f * ax);
    float t = (1.0f - e) / (1.0f + e);
    return copysignf(t, x);
}

__device__ __forceinline__ unsigned short f2b(float f) {
    union { float f; unsigned u; } v; v.f = f;
    unsigned r = (v.u + 0x7FFF + ((v.u >> 16) & 1)) >> 16;
    return (unsigned short)r;
}

__device__ __forceinline__ float4 ntload4(const float4* p) {
    f32x4 v = __builtin_nontemporal_load((const f32x4*)p);
    float4 r; r.x = v.x; r.y = v.y; r.z = v.z; r.w = v.w;
    return r;
}

// ---------------- setup: bf16 weight transposes ----------------
__global__ void k_setup(const float* __restrict__ fw0, const float* __restrict__ fw1,
                        unsigned short* __restrict__ fw0Tb, unsigned short* __restrict__ fw0b,
                        unsigned short* __restrict__ fw1Tb, unsigned short* __restrict__ fw1Nb) {
    int idx = blockIdx.x * 256 + threadIdx.x;
    if (idx < NTYPES * FHD * DD) {           // fw0Tb [t][o][d] <- fw0[t][d][o]
        int t = idx / (FHD * DD);
        int r = idx % (FHD * DD);
        int o = r / DD, d = r % DD;
        fw0Tb[(long)t * 256 * DD + (long)o * DD + d] =
            f2b(fw0[(long)t * DD * FHD + (long)d * FHD + o]);
    }
    if (idx < NTYPES * DD * 256) {           // fw0b [t][d][kk] (kk>=240 -> 0)
        int t = idx / (DD * 256);
        int r = idx % (DD * 256);
        int d = r / 256, kk = r % 256;
        float v = (kk < FHD) ? fw0[(long)t * DD * FHD + (long)d * FHD + kk] : 0.f;
        fw0b[idx] = f2b(v);
    }
    if (idx < NTYPES * FHD * 256) {          // fw1Tb [t][o][kk] = fw1[kk][o], pad 0
        int t = idx / (FHD * 256);
        int r = idx % (FHD * 256);
        int o = r / 256, kk = r % 256;
        float v = (kk < FHD) ? fw1[(long)t * FHD * FHD + (long)kk * FHD + o] : 0.f;
        fw1Tb[(long)t * 256 * 256 + (long)o * 256 + kk] = f2b(v);
    }
    if (idx < NTYPES * 256 * 256) {          // fw1Nb [t][i][kk] = fw1[i][kk], pad 0 both dims
        int t = idx / (256 * 256);
        int r = idx % (256 * 256);
        int i = r / 256, kk = r % 256;
        float v = (i < FHD && kk < FHD) ? fw1[(long)t * FHD * FHD + (long)i * FHD + kk] : 0.f;
        fw1Nb[(long)t * 256 * 256 + (long)i * 256 + kk] = f2b(v);
    }
}

// ---------------- table stage 1 ----------------
__global__ __launch_bounds__(256) void k_table_h(
    const float* __restrict__ ew0, const float* __restrict__ eb0,
    const float* __restrict__ ew1, const float* __restrict__ eb1,
    const float* __restrict__ tv)
{
    int idx = blockIdx.x * 256 + threadIdx.x;
    if (idx >= NTYPES * NK) return;
    int t = idx / NK, i = idx % NK;
    float s = S_MIN + (float)i * S_H;

    float h0[E0], t0[E0];
#pragma unroll
    for (int k = 0; k < E0; ++k) {
        float c = eb0[k];
#pragma unroll
        for (int f = 0; f < TFD; ++f) c = fmaf(tv[t * TFD + f], ew0[(1 + f) * E0 + k], c);
        float h = ftanh(fmaf(s, ew0[k], c));
        h0[k] = h;
        t0[k] = (1.f - h * h) * ew0[k];
    }
#pragma unroll 2
    for (int l = 0; l < E1; ++l) {
        float acc = eb1[l], dacc = 0.f;
#pragma unroll
        for (int k = 0; k < E0; ++k) {
            float w = ew1[k * E1 + l];
            acc = fmaf(h0[k], w, acc);
            dacc = fmaf(t0[k], w, dacc);
        }
        float h = ftanh(acc);
        g_th1[(long)idx * E1 + l] = make_float2(h, (1.f - h * h) * dacc);
    }
}

// ---------------- table stage 2 ----------------
__global__ __launch_bounds__(256) void k_table_g(
    const float* __restrict__ ew2, const float* __restrict__ eb2)
{
    long idx = (long)blockIdx.x * 256 + threadIdx.x;
    if (idx >= (long)NTYPES * NK * GD) return;
    int g = idx % GD;
    long ti = idx / GD;
    int i = ti % NK;

    const float2* hv = g_th1 + ti * E1;
    float acc = eb2[g], dacc = 0.f;
#pragma unroll 5
    for (int l = 0; l < E1; ++l) {
        float2 x = hv[l];
        float w = ew2[l * GD + g];
        acc = fmaf(x.x, w, acc);
        dacc = fmaf(x.y, w, dacc);
    }
    float G = ftanh(acc);
    float dv = (1.f - G * G) * dacc;

    float2* f2 = (float2*)g_tab4;
    long e = ti * GD + g;
    f2[2 * e] = make_float2(G, dv);
    if (i > 0) f2[2 * (e - GD) + 1] = make_float2(G, dv);
}

// ---------------- table stage 3: fp16 packed table ----------------
__global__ __launch_bounds__(256) void k_table_h16() {
    long idx = (long)blockIdx.x * 256 + threadIdx.x;
    if (idx >= (long)NTYPES * NK * HCH) return;
    int g = idx % HCH;
    long ti = idx / HCH;
    _Float16* dst = h_tab + idx * 4;
    if (g >= GD) {
        dst[0] = (_Float16)0.f; dst[1] = (_Float16)0.f;
        dst[2] = (_Float16)0.f; dst[3] = (_Float16)0.f;
        return;
    }
    float4 r = g_tab4[ti * GD + g];     // (G_i, dv_i, G_{i+1}, dv_{i+1})
    dst[0] = (_Float16)r.x;
    dst[1] = (_Float16)(r.z - r.x);     // dG (avoids fp16 cancellation on d00 term)
    dst[2] = (_Float16)r.y;
    dst[3] = (_Float16)r.w;
}

__device__ __forceinline__ int hermite6(float s,
    float& c01, float& c10, float& c11,
    float& d00, float& d10, float& d11)
{
    float x = (s - S_MIN) * S_INVH;
    x = fminf(fmaxf(x, 0.f), (float)(NK - 1) - 1e-3f);
    int i = (int)x;
    float u = x - (float)i;
    float um = 1.f - u;
    c01 = u * u * (3.f - 2.f * u);
    c10 = S_H * u * um * um;
    c11 = S_H * u * u * (u - 1.f);
    d00 = (6.f * u * u - 6.f * u) * S_INVH;
    d10 = fmaf(3.f * u, u, fmaf(-4.f, u, 1.f));
    d11 = fmaf(3.f * u, u, -2.f * u);
    return i;
}

// ---------------- K1: LDS-precomputed basis; lane = channel-pair ----------------
__global__ __launch_bounds__(256) void k1_emb(
    const float* __restrict__ Ri,
    unsigned short* __restrict__ drb, float* __restrict__ xa_ws)
{
    __shared__ float4 a4s[JN];
    __shared__ uint2 cpak[JN];
    __shared__ int rowoff[JN];
    __shared__ float xar[4 * 400];
    __shared__ float xas[400];

    int tid = threadIdx.x;
    int lane = tid & 63;
    int w = tid >> 6;
    int n = blockIdx.x;

    if (tid < JN) {
        float4 a = ((const float4*)Ri)[(long)n * JN + tid];
        a4s[tid] = a;
        float c01, c10, c11, d00, d10, d11;
        int ik = hermite6(a.x, c01, c10, c11, d00, d10, d11);
        rowoff[tid] = ((tid / MAXNB) * NK + ik) * (HCH / 2);
        h16x2 cP; cP[0] = (_Float16)1.f;  cP[1] = (_Float16)c01;
        h16x2 cQ; cQ[0] = (_Float16)c10;  cQ[1] = (_Float16)c11;
        cpak[tid] = make_uint2(h2u(cP), h2u(cQ));
    }
    __syncthreads();

    float xe0 = 0.f, xe1 = 0.f, xe2 = 0.f, xe3 = 0.f;
    float xo0 = 0.f, xo1 = 0.f, xo2 = 0.f, xo3 = 0.f;

#pragma unroll 4
    for (int ii = 0; ii < 50; ++ii) {
        int j = w * 50 + ii;
        uint2 cc = cpak[j];
        const uint4* row4 = (const uint4*)h_tab + rowoff[j];
        if (lane < 50) {
            uint4 v = row4[lane];
            float4 a = a4s[j];
            float Ge = FDOT2(as_h2(v.y), as_h2(cc.y), FDOT2(as_h2(v.x), as_h2(cc.x), 0.f));
            float Go = FDOT2(as_h2(v.w), as_h2(cc.y), FDOT2(as_h2(v.z), as_h2(cc.x), 0.f));
            xe0 = fmaf(a.x, Ge, xe0); xe1 = fmaf(a.y, Ge, xe1);
            xe2 = fmaf(a.z, Ge, xe2); xe3 = fmaf(a.w, Ge, xe3);
            xo0 = fmaf(a.x, Go, xo0); xo1 = fmaf(a.y, Go, xo1);
            xo2 = fmaf(a.z, Go, xo2); xo3 = fmaf(a.w, Go, xo3);
        }
    }

    float* xw = xar + w * 400;
    if (lane < 50) {
        *(float2*)&xw[0 * GD + 2 * lane] = make_float2(xe0, xo0);
        *(float2*)&xw[1 * GD + 2 * lane] = make_float2(xe1, xo1);
        *(float2*)&xw[2 * GD + 2 * lane] = make_float2(xe2, xo2);
        *(float2*)&xw[3 * GD + 2 * lane] = make_float2(xe3, xo3);
    }
    __syncthreads();

    for (int i = tid; i < 400; i += 256) {
        float v = (xar[i] + xar[400 + i] + xar[800 + i] + xar[1200 + i]) * INV200;
        xas[i] = v;
        xa_ws[(long)n * 400 + i] = v;
    }
    __syncthreads();

    for (int i = tid; i < DD; i += 256) {
        int gg = i / M2D, m = i % M2D;
        float v = 0.f;
#pragma unroll
        for (int c = 0; c < 4; ++c) v = fmaf(xas[c * GD + gg], xas[c * GD + m], v);
        drb[(long)n * DD + i] = f2b(v);
    }
}

// ---------------- MFMA bf16 GEMM: C = act(A @ BT^T + bias) ----------------
// mode: 0 = none, 1 = tanh, 2 = v *= (1 - x^2) with x = X[row][col] (dh0g path).
__global__ __launch_bounds__(256) void mgemm(
    const unsigned short* __restrict__ Ab, const unsigned short* __restrict__ BTb,
    const float* __restrict__ biasb, float* __restrict__ Cb, unsigned short* __restrict__ Cbf,
    const float* __restrict__ Xb,
    int M, int N, int K, int Npad,
    long sA, long sBT, long sBias, long sC, long sCbf, long sX, int mode)
{
    int t = blockIdx.z;
    const unsigned short* A = Ab + (long)t * sA;
    const unsigned short* BT = BTb + (long)t * sBT;
    const float* bias = biasb ? biasb + (long)t * sBias : nullptr;
    float* C = Cb ? Cb + (long)t * sC : nullptr;
    unsigned short* Cb16 = Cbf ? Cbf + (long)t * sCbf : nullptr;
    const float* X = Xb ? Xb + (long)t * sX : nullptr;

    __shared__ __align__(16) unsigned short As[64 * 72];
    __shared__ __align__(16) unsigned short Bs[64 * 72];

    int tid = threadIdx.x;
    int m0 = blockIdx.x * 64;
    int n0 = blockIdx.y * 64;

    int lane = tid & 63;
    int w = tid >> 6;
    int wm = (w & 1) * 32;
    int wn = (w >> 1) * 32;
    int fm = lane & 15;
    int q = lane >> 4;

    f32x4 acc[2][2] = {};

    int sr = tid >> 2;
    int sc = tid & 3;

    const unsigned short* Ar = A + (long)(m0 + sr) * K + sc * 8;
    const unsigned short* Br = BT + (long)(n0 + sr) * K + sc * 8;
    unsigned short* Asw = As + sr * 72 + sc * 8;
    unsigned short* Bsw = Bs + sr * 72 + sc * 8;

    for (int k0 = 0; k0 < K; k0 += 64) {
        uint4 av0 = *(const uint4*)(Ar + k0);
        uint4 av1 = *(const uint4*)(Ar + k0 + 32);
        uint4 bv0 = *(const uint4*)(Br + k0);
        uint4 bv1 = *(const uint4*)(Br + k0 + 32);
        __syncthreads();
        *(uint4*)(Asw) = av0;
        *(uint4*)(Asw + 32) = av1;
        *(uint4*)(Bsw) = bv0;
        *(uint4*)(Bsw + 32) = bv1;
        __syncthreads();
#pragma unroll
        for (int kk = 0; kk < 64; kk += 32) {
            bf16x8 af0 = *(const bf16x8*)(As + (wm + fm) * 72 + kk + q * 8);
            bf16x8 af1 = *(const bf16x8*)(As + (wm + 16 + fm) * 72 + kk + q * 8);
            bf16x8 bg0 = *(const bf16x8*)(Bs + (wn + fm) * 72 + kk + q * 8);
            bf16x8 bg1 = *(const bf16x8*)(Bs + (wn + 16 + fm) * 72 + kk + q * 8);
            acc[0][0] = __builtin_amdgcn_mfma_f32_16x16x32_bf16(af0, bg0, acc[0][0], 0, 0, 0);
            acc[0][1] = __builtin_amdgcn_mfma_f32_16x16x32_bf16(af0, bg1, acc[0][1], 0, 0, 0);
            acc[1][0] = __builtin_amdgcn_mfma_f32_16x16x32_bf16(af1, bg0, acc[1][0], 0, 0, 0);
            acc[1][1] = __builtin_amdgcn_mfma_f32_16x16x32_bf16(af1, bg1, acc[1][1], 0, 0, 0);
        }
    }

    // C/D layout: col = lane&15, row = q*4 + reg
#pragma unroll
    for (int i = 0; i < 2; ++i) {
#pragma unroll
        for (int j = 0; j < 2; ++j) {
            int col = n0 + wn + j * 16 + fm;
            int rb = m0 + wm + i * 16 + q * 4;
            bool ok = col < N;
            float bv = (bias && ok) ? bias[col] : 0.f;
#pragma unroll
            for (int r = 0; r < 4; ++r) {
                float v = acc[i][j][r] + bv;
                if (mode == 1) {
                    v = ftanh(v);
                } else if (mode == 2 && ok) {
                    float x = X[(long)(rb + r) * N + col];
                    v *= (1.f - x * x);
                }
                if (ok && C) C[(long)(rb + r) * N + col] = v;
                if (Cb16) Cb16[(long)(rb + r) * Npad + col] = ok ? f2b(v) : (unsigned short)0;
            }
        }
    }
}

// ---------------- K3a (lite): per-atom Ei + Etot + u1 (bf16, K zero-padded) --------
// R10 insight: the old k3a's 240-iter serial matvec (dh0g) is a GEMM -- moved to
// mgemm mode 2. Here only the elementwise u1 = fw2*(1-fh1^2) + the Ei reduction.
__global__ __launch_bounds__(256) void k3a(
    const float* __restrict__ fh1, const float* __restrict__ fw2,
    const float* __restrict__ fb2,
    float* __restrict__ out, unsigned short* __restrict__ u1b)
{
    int n = blockIdx.x;
    int t = n / NA;
    int tid = threadIdx.x;
    __shared__ float red[256];

    float p = 0.f, u1 = 0.f;
    if (tid < FHD) {
        float h1v = fh1[(long)n * FHD + tid];
        float w2v = fw2[t * FHD + tid];
        p = h1v * w2v;
        u1 = w2v * (1.f - h1v * h1v);
    }
    u1b[(long)n * 256 + tid] = (tid < FHD) ? f2b(u1) : (unsigned short)0;
    red[tid] = p;
    __syncthreads();
    for (int off = 128; off > 0; off >>= 1) {
        if (tid < off) red[tid] += red[tid + off];
        __syncthreads();
    }
    if (tid == 0) {
        float e = red[0] + fb2[t];
        out[OUT_EI + n] = e;
        atomicAdd(out, e);
    }
}

// ---------------- K3b: per-atom P, g-major float4 [n][g][c] ----------------
__global__ __launch_bounds__(256) void k3b(
    const float* __restrict__ Q, const float* __restrict__ xa, float* __restrict__ P4)
{
    int n = blockIdx.x;
    int tid = threadIdx.x;
    __shared__ float qs[DD];
    __shared__ float xs[400];
    for (int i = tid; i < DD; i += 256) qs[i] = Q[(long)n * DD + i];
    for (int i = tid; i < 400; i += 256) xs[i] = xa[(long)n * 400 + i];
    __syncthreads();
    for (int i = tid; i < 400; i += 256) {
        int c = i / GD, g = i % GD;
        float acc = 0.f;
        for (int m = 0; m < M2D; ++m) acc = fmaf(qs[g * M2D + m], xs[c * GD + m], acc);
        if (g < M2D) {
            for (int g2 = 0; g2 < GD; ++g2) acc = fmaf(qs[g2 * M2D + g], xs[c * GD + g2], acc);
        }
        P4[((long)n * GD + g) * 4 + c] = acc * INV200;
    }
}

// ---------------- K4 tail: dEdx + scatter + virial for one item ----------------
__device__ __forceinline__ void k4_tail(
    int n, int j, float4 a,
    float M10, float M11, float M12, float M13,
    float M20, float M21, float M22, float M23,
    const float* __restrict__ dfeat, const float* __restrict__ ImageDR,
    const int* __restrict__ list_neigh, float* __restrict__ out, int ql,
    float& f0, float& f1, float& f2v,
    float& v00, float& v01, float& v02, float& v11, float& v12, float& v22)
{
    float ds = a.x * M20 + a.y * M21 + a.z * M22 + a.w * M23;
    float dEda0 = M10 + ds, dEda1 = M11, dEda2 = M12, dEda3 = M13;

    long item = (long)n * JN + j;
    if (ql < 3) {
        const float* dfp = dfeat + item * 12 + ql;   // df[c][ql], stride 3
        float w0 = __builtin_nontemporal_load(dfp);
        float w1 = __builtin_nontemporal_load(dfp + 3);
        float w2 = __builtin_nontemporal_load(dfp + 6);
        float w3 = __builtin_nontemporal_load(dfp + 9);
        float dEdx = dEda0 * w0 + dEda1 * w1 + dEda2 * w2 + dEda3 * w3;

        // self-force: accumulated for ALL items (mask applies to scatter only)
        if (ql == 0) f0 += dEdx;
        else if (ql == 1) f1 += dEdx;
        else f2v += dEdx;

        int ln = __builtin_nontemporal_load(list_neigh + item);
        if (ln > 0) {
            int ii2 = ln - 1;
            if (ii2 > NATOMS - 1) ii2 = NATOMS - 1;
            atomicAdd(&out[OUT_F + ii2 * 3 + ql], dEdx);
            float im0 = __builtin_nontemporal_load(ImageDR + item * 3);
            float im1 = __builtin_nontemporal_load(ImageDR + item * 3 + 1);
            float im2 = __builtin_nontemporal_load(ImageDR + item * 3 + 2);
            if (ql == 0) {
                v00 += im0 * dEdx;
            } else if (ql == 1) {
                v01 += im0 * dEdx; v11 += im1 * dEdx;
            } else {
                v02 += im0 * dEdx; v12 += im1 * dEdx; v22 += im2 * dEdx;
            }
        }
    }
}

// ---------------- K4: quad-per-item, fp16 table + fdot2, FENCED burst-13 ----------
// R7 internals (124us proven). launch_bounds min-waves 4 -> 6: VGPR cap 85 (>=64
// used), should lift occupancy 39% -> ~60% and, if k4 is latency-bound, cut dur to
// ~100us; if dur stays flat, TA line-throughput saturation is confirmed (k4 floor).
__global__ __launch_bounds__(256, 6) void k4(
    const float* __restrict__ Ri, const float* __restrict__ dfeat,
    const float* __restrict__ ImageDR, const int* __restrict__ list_neigh,
    const float4* __restrict__ P4ws, float* __restrict__ out)
{
    __shared__ float4 a4s[JN];
    __shared__ float4 P4s[HCH];
    __shared__ float fred[4][3];
    __shared__ float vred[4][6];
    __shared__ float vacc[6];

    int tid = threadIdx.x;
    int lane = tid & 63;
    int w = tid >> 6;
    int n = blockIdx.x;

    if (tid < JN) a4s[tid] = ntload4(&((const float4*)Ri)[(long)n * JN + tid]);
    if (tid < HCH)
        P4s[tid] = (tid < GD) ? ntload4(&P4ws[(long)n * GD + tid])
                              : make_float4(0.f, 0.f, 0.f, 0.f);
    __syncthreads();

    int ql = lane & 3;
    int qid = w * 16 + (lane >> 2);   // block-wide quad id: 0..63

    float f0 = 0.f, f1 = 0.f, f2v = 0.f;
    float v00 = 0.f, v01 = 0.f, v02 = 0.f, v11 = 0.f, v12 = 0.f, v22 = 0.f;

    for (int pass = 0; pass < 4; ++pass) {
        int j;
        if (pass < 3) {
            j = pass * 64 + qid;          // 0..191
        } else {
            if (qid & 7) break;           // 8 quads spread over the 4 waves
            j = 192 + (qid >> 3);         // 192..199
        }

        float4 a = a4s[j];
        float c01, c10, c11, d00, d10, d11;
        int ik = hermite6(a.x, c01, c10, c11, d00, d10, d11);
        const uint4* row4 = (const uint4*)h_tab + (long)((j / MAXNB) * NK + ik) * (HCH / 2);

        h16x2 cP; cP[0] = (_Float16)1.f;   cP[1] = (_Float16)c01;
        h16x2 cQ; cQ[0] = (_Float16)c10;   cQ[1] = (_Float16)c11;
        h16x2 cR; cR[0] = (_Float16)0.f;   cR[1] = (_Float16)(-d00);
        h16x2 cS; cS[0] = (_Float16)d10;   cS[1] = (_Float16)d11;

        float M10 = 0.f, M11 = 0.f, M12 = 0.f, M13 = 0.f;
        float M20 = 0.f, M21 = 0.f, M22 = 0.f, M23 = 0.f;

        // ---- fenced burst: issue all 13 row loads before ANY compute ----
        uint4 r[13];
#pragma unroll
        for (int i2 = 0; i2 < 13; ++i2) r[i2] = row4[4 * i2 + ql];
        __builtin_amdgcn_sched_barrier(0);

#pragma unroll
        for (int i2 = 0; i2 < 13; ++i2) {
            int ca = 8 * i2 + 2 * ql;
            float4 pa = P4s[ca];
            float4 pb = P4s[ca + 1];
            float G1 = FDOT2(as_h2(r[i2].y), cQ, FDOT2(as_h2(r[i2].x), cP, 0.f));
            float D1 = FDOT2(as_h2(r[i2].y), cS, FDOT2(as_h2(r[i2].x), cR, 0.f));
            M10 = fmaf(pa.x, G1, M10); M11 = fmaf(pa.y, G1, M11);
            M12 = fmaf(pa.z, G1, M12); M13 = fmaf(pa.w, G1, M13);
            M20 = fmaf(pa.x, D1, M20); M21 = fmaf(pa.y, D1, M21);
            M22 = fmaf(pa.z, D1, M22); M23 = fmaf(pa.w, D1, M23);
            float G2 = FDOT2(as_h2(r[i2].w), cQ, FDOT2(as_h2(r[i2].z), cP, 0.f));
            float D2 = FDOT2(as_h2(r[i2].w), cS, FDOT2(as_h2(r[i2].z), cR, 0.f));
            M10 = fmaf(pb.x, G2, M10); M11 = fmaf(pb.y, G2, M11);
            M12 = fmaf(pb.z, G2, M12); M13 = fmaf(pb.w, G2, M13);
            M20 = fmaf(pb.x, D2, M20); M21 = fmaf(pb.y, D2, M21);
            M22 = fmaf(pb.z, D2, M22); M23 = fmaf(pb.w, D2, M23);
        }
        __builtin_amdgcn_sched_barrier(0);

        // intra-quad butterfly: all 4 lanes end with the full channel sums
#pragma unroll
        for (int mask = 1; mask <= 2; mask <<= 1) {
            M10 += __shfl_xor(M10, mask); M11 += __shfl_xor(M11, mask);
            M12 += __shfl_xor(M12, mask); M13 += __shfl_xor(M13, mask);
            M20 += __shfl_xor(M20, mask); M21 += __shfl_xor(M21, mask);
            M22 += __shfl_xor(M22, mask); M23 += __shfl_xor(M23, mask);
        }

        k4_tail(n, j, a, M10, M11, M12, M13, M20, M21, M22, M23,
                dfeat, ImageDR, list_neigh, out, ql, f0, f1, f2v,
                v00, v01, v02, v11, v12, v22);
    }

    // wave butterfly over self-force + virial partials (roles distributed per-lane;
    // the sum over all lanes recovers each slot's total)
#pragma unroll
    for (int mask = 32; mask > 0; mask >>= 1) {
        f0 += __shfl_xor(f0, mask);
        f1 += __shfl_xor(f1, mask);
        f2v += __shfl_xor(f2v, mask);
        v00 += __shfl_xor(v00, mask);
        v01 += __shfl_xor(v01, mask);
        v02 += __shfl_xor(v02, mask);
        v11 += __shfl_xor(v11, mask);
        v12 += __shfl_xor(v12, mask);
        v22 += __shfl_xor(v22, mask);
    }
    if (lane == 0) {
        fred[w][0] = f0; fred[w][1] = f1; fred[w][2] = f2v;
        vred[w][0] = v00; vred[w][1] = v01; vred[w][2] = v02;
        vred[w][3] = v11; vred[w][4] = v12; vred[w][5] = v22;
    }
    __syncthreads();
    if (tid < 3) {
        float s = fred[0][tid] + fred[1][tid] + fred[2][tid] + fred[3][tid];
        atomicAdd(&out[OUT_F + n * 3 + tid], -s);
    }
    if (tid < 6) {
        vacc[tid] = vred[0][tid] + vred[1][tid] + vred[2][tid] + vred[3][tid];
    }
    __syncthreads();
    if (tid < 9) {
        const int vmap[9] = {0, 1, 2, 1, 3, 4, 2, 4, 5};
        atomicAdd(&out[OUT_V + tid], vacc[vmap[tid]]);
    }
}

extern "C" void kernel_launch(void* const* d_in, const int* in_sizes, int n_in,
                              void* d_out, int out_size, void* d_ws, size_t ws_size,
                              hipStream_t stream) {
    const float* Ri = (const float*)d_in[0];
    const float* dfeat = (const float*)d_in[1];
    const float* ImageDR = (const float*)d_in[2];
    const float* tv = (const float*)d_in[3];
    const float* ew0 = (const float*)d_in[4];
    const float* eb0 = (const float*)d_in[5];
    const float* ew1 = (const float*)d_in[6];
    const float* eb1 = (const float*)d_in[7];
    const float* ew2 = (const float*)d_in[8];
    const float* eb2 = (const float*)d_in[9];
    const float* fw0 = (const float*)d_in[10];
    const float* fb0 = (const float*)d_in[11];
    const float* fw1 = (const float*)d_in[12];
    const float* fb1 = (const float*)d_in[13];
    const float* fw2 = (const float*)d_in[14];
    const float* fb2 = (const float*)d_in[15];
    const int* list_neigh = (const int*)d_in[16];

    float* out = (float*)d_out;
    float* ws = (float*)d_ws;
    float* Q = ws + WS_Q;
    unsigned short* fw1Nb = (unsigned short*)(ws + WS_FW1NB);
    unsigned short* drb = (unsigned short*)(ws + WS_DRB);
    unsigned short* u1b = (unsigned short*)(ws + WS_U1B);
    float* xa = ws + WS_XA;
    float* P = ws + WS_P;
    float* fh0 = ws + WS_FH0;
    float* fh1 = ws + WS_FH1;
    unsigned short* dh0gb = (unsigned short*)(ws + WS_DH0GB);
    unsigned short* fh0b = (unsigned short*)(ws + WS_FH0B);
    unsigned short* fw0Tb = (unsigned short*)(ws + WS_FW0TB);
    unsigned short* fw0b = (unsigned short*)(ws + WS_FW0B);
    unsigned short* fw1Tb = (unsigned short*)(ws + WS_FW1TB);

    hipMemsetAsync(d_out, 0, (size_t)out_size * sizeof(float), stream);

    k_setup<<<(NTYPES * DD * 256 + 255) / 256, 256, 0, stream>>>(
        fw0, fw1, fw0Tb, fw0b, fw1Tb, fw1Nb);
    k_table_h<<<(NTYPES * NK + 255) / 256, 256, 0, stream>>>(ew0, eb0, ew1, eb1, tv);
    k_table_g<<<(NTYPES * NK * GD + 255) / 256, 256, 0, stream>>>(ew2, eb2);
    k_table_h16<<<(NTYPES * NK * HCH + 255) / 256, 256, 0, stream>>>();

    k1_emb<<<NATOMS, 256, 0, stream>>>(Ri, drb, xa);

    // fh0 = tanh(dr @ fw0 + fb0)  [+ bf16 copy for next GEMM]
    mgemm<<<dim3(32, 4, 2), 256, 0, stream>>>(
        drb, fw0Tb, fb0, fh0, fh0b, nullptr,
        2048, 240, 1600, 256,
        2048L * 1600, 256L * 1600, 240L, 2048L * 240, 2048L * 256, 0L, 1);
    // fh1 = tanh(fh0 @ fw1 + fb1)
    mgemm<<<dim3(32, 4, 2), 256, 0, stream>>>(
        fh0b, fw1Tb, fb1, fh1, nullptr, nullptr,
        2048, 240, 256, 0,
        2048L * 256, 256L * 256, 240L, 2048L * 240, 0L, 0L, 1);

    // Ei/Etot + u1 (elementwise)
    k3a<<<NATOMS, 256, 0, stream>>>(fh1, fw2, fb2, out, u1b);

    // dh0g = (u1 @ fw1^T) * (1 - fh0^2)  -> bf16 dh0gb (K zero-padded)
    mgemm<<<dim3(32, 4, 2), 256, 0, stream>>>(
        u1b, fw1Nb, nullptr, nullptr, dh0gb, fh0,
        2048, 240, 256, 256,
        2048L * 256, 256L * 256, 0L, 0L, 2048L * 256, 2048L * 240, 2);

    // Q = dh0g @ fw0^T
    mgemm<<<dim3(32, 25, 2), 256, 0, stream>>>(
        dh0gb, fw0b, nullptr, Q, nullptr, nullptr,
        2048, 1600, 256, 0,
        2048L * 256, 1600L * 256, 0L, 2048L * 1600, 0L, 0L, 0);

    k3b<<<NATOMS, 256, 0, stream>>>(Q, xa, P);

    k4<<<NATOMS, 256, 0, stream>>>(Ri, dfeat, ImageDR, list_neigh,
        (const float4*)P, out);
}

// Round 12
// 423.396 us; speedup vs baseline: 1.5960x; 1.5960x over previous
//
#include <hip/hip_runtime.h>

// Problem constants
#define NATOMS 4096
#define NTYPES 2
#define NA 2048
#define MAXNB 100
#define JN 200          // neighbors per atom
#define TFD 4
#define E0 25
#define E1 50
#define GD 100
#define M2D 16
#define DD 1600
#define FHD 240
#define INV200 (1.0f/200.0f)

// Output layout (floats): Etot@0 (1), Ei@1 (4096), F@4097 (12288), Virial@16385 (9)
#define OUT_EI 1
#define OUT_F 4097
#define OUT_V 16385

// Workspace layout (floats). Total ~17.0M floats = 68 MB.
#define WS_Q 0L                  // Q fp32 [2][2048][1600] (written by gemmQ)
#define WS_FW1NB 0L              // bf16 fw1Nb [2][256][256] aliases Q head; consumed by dh0g-gemm BEFORE gemmQ
#define WS_DRB 6553600L          // dr bf16 [2][2048][1600] (k1 -> mgemm fh0)
#define WS_U1B 6553600L          // bf16 u1 [4096][256] aliases drb head; written AFTER fh0-gemm consumed drb
#define WS_XA 9830400L           // 4096*400
#define WS_P 11468800L           // 4096*400 (g-major float4 [n][g][c])
#define WS_FH0 13107200L         // fp32 [4096][240]
#define WS_FH1 14090240L         // fp32 [4096][240]
#define WS_DH0GB 15073280L       // bf16 [2][2048][256] zero-padded K
#define WS_FH0B 15597568L        // bf16 [2][2048][256] zero-padded K
#define WS_FW0TB 16121856L       // bf16 [2][256][1600] (rows>=240 garbage-ok)
#define WS_FW0B 16531456L        // bf16 [2][1600][256] (cols>=240 zero)
#define WS_FW1TB 16941056L       // bf16 [2][256][256] (cols>=240 zero, rows>=240 garbage-ok)

// G(s) lookup table: 1-D function of s per type (temb const per type).
#define NK 1024
#define S_MIN (-8.0f)
#define S_H 0.015625f
#define S_INVH 64.0f
#define HCH 104                  // channels padded to 13*8 for fp16 table
__device__ float4 g_tab4[NTYPES * NK * GD];
__device__ float2 g_th1[NTYPES * NK * E1];
// fp16 table: [t][knot][ch][4] = (G_i, dG=G_{i+1}-G_i, dv_i, dv_{i+1})
__device__ _Float16 h_tab[NTYPES * NK * HCH * 4];

typedef __attribute__((ext_vector_type(8))) short bf16x8;
typedef __attribute__((ext_vector_type(4))) float f32x4;
typedef __attribute__((ext_vector_type(2))) _Float16 h16x2;

#if defined(__has_builtin)
#if __has_builtin(__builtin_amdgcn_fdot2)
#define HAVE_FDOT2 1
#endif
#endif
#ifdef HAVE_FDOT2
#define FDOT2(a, b, c) __builtin_amdgcn_fdot2((a), (b), (c), false)
#else
__device__ __forceinline__ float fdot2_sw(h16x2 a, h16x2 b, float c) {
    return fmaf((float)a[0], (float)b[0], fmaf((float)a[1], (float)b[1], c));
}
#define FDOT2(a, b, c) fdot2_sw((a), (b), (c))
#endif

__device__ __forceinline__ h16x2 as_h2(unsigned u) {
    union { unsigned u; h16x2 h; } v; v.u = u; return v.h;
}

__device__ __forceinline__ unsigned h2u(h16x2 h) {
    union { h16x2 h; unsigned u; } v; v.h = h; return v.u;
}

__device__ __forceinline__ float ftanh(float x) {
    float ax = fabsf(x);
    float e = __expf(-2.0f * ax);
    float t = (1.0f - e) / (1.0f + e);
    return copysignf(t, x);
}

__device__ __forceinline__ unsigned short f2b(float f) {
    union { float f; unsigned u; } v; v.f = f;
    unsigned r = (v.u + 0x7FFF + ((v.u >> 16) & 1)) >> 16;
    return (unsigned short)r;
}

__device__ __forceinline__ float4 ntload4(const float4* p) {
    f32x4 v = __builtin_nontemporal_load((const f32x4*)p);
    float4 r; r.x = v.x; r.y = v.y; r.z = v.z; r.w = v.w;
    return r;
}

// ---------------- setup: bf16 weight transposes ----------------
__global__ void k_setup(const float* __restrict__ fw0, const float* __restrict__ fw1,
                        unsigned short* __restrict__ fw0Tb, unsigned short* __restrict__ fw0b,
                        unsigned short* __restrict__ fw1Tb, unsigned short* __restrict__ fw1Nb) {
    int idx = blockIdx.x * 256 + threadIdx.x;
    if (idx < NTYPES * FHD * DD) {           // fw0Tb [t][o][d] <- fw0[t][d][o]
        int t = idx / (FHD * DD);
        int r = idx % (FHD * DD);
        int o = r / DD, d = r % DD;
        fw0Tb[(long)t * 256 * DD + (long)o * DD + d] =
            f2b(fw0[(long)t * DD * FHD + (long)d * FHD + o]);
    }
    if (idx < NTYPES * DD * 256) {           // fw0b [t][d][kk] (kk>=240 -> 0)
        int t = idx / (DD * 256);
        int r = idx % (DD * 256);
        int d = r / 256, kk = r % 256;
        float v = (kk < FHD) ? fw0[(long)t * DD * FHD + (long)d * FHD + kk] : 0.f;
        fw0b[idx] = f2b(v);
    }
    if (idx < NTYPES * FHD * 256) {          // fw1Tb [t][o][kk] = fw1[kk][o], pad 0
        int t = idx / (FHD * 256);
        int r = idx % (FHD * 256);
        int o = r / 256, kk = r % 256;
        float v = (kk < FHD) ? fw1[(long)t * FHD * FHD + (long)kk * FHD + o] : 0.f;
        fw1Tb[(long)t * 256 * 256 + (long)o * 256 + kk] = f2b(v);
    }
    if (idx < NTYPES * 256 * 256) {          // fw1Nb [t][i][kk] = fw1[i][kk], pad 0 both dims
        int t = idx / (256 * 256);
        int r = idx % (256 * 256);
        int i = r / 256, kk = r % 256;
        float v = (i < FHD && kk < FHD) ? fw1[(long)t * FHD * FHD + (long)i * FHD + kk] : 0.f;
        fw1Nb[(long)t * 256 * 256 + (long)i * 256 + kk] = f2b(v);
    }
}

// ---------------- table stage 1 ----------------
__global__ __launch_bounds__(256) void k_table_h(
    const float* __restrict__ ew0, const float* __restrict__ eb0,
    const float* __restrict__ ew1, const float* __restrict__ eb1,
    const float* __restrict__ tv)
{
    int idx = blockIdx.x * 256 + threadIdx.x;
    if (idx >= NTYPES * NK) return;
    int t = idx / NK, i = idx % NK;
    float s = S_MIN + (float)i * S_H;

    float h0[E0], t0[E0];
#pragma unroll
    for (int k = 0; k < E0; ++k) {
        float c = eb0[k];
#pragma unroll
        for (int f = 0; f < TFD; ++f) c = fmaf(tv[t * TFD + f], ew0[(1 + f) * E0 + k], c);
        float h = ftanh(fmaf(s, ew0[k], c));
        h0[k] = h;
        t0[k] = (1.f - h * h) * ew0[k];
    }
#pragma unroll 2
    for (int l = 0; l < E1; ++l) {
        float acc = eb1[l], dacc = 0.f;
#pragma unroll
        for (int k = 0; k < E0; ++k) {
            float w = ew1[k * E1 + l];
            acc = fmaf(h0[k], w, acc);
            dacc = fmaf(t0[k], w, dacc);
        }
        float h = ftanh(acc);
        g_th1[(long)idx * E1 + l] = make_float2(h, (1.f - h * h) * dacc);
    }
}

// ---------------- table stage 2 ----------------
__global__ __launch_bounds__(256) void k_table_g(
    const float* __restrict__ ew2, const float* __restrict__ eb2)
{
    long idx = (long)blockIdx.x * 256 + threadIdx.x;
    if (idx >= (long)NTYPES * NK * GD) return;
    int g = idx % GD;
    long ti = idx / GD;
    int i = ti % NK;

    const float2* hv = g_th1 + ti * E1;
    float acc = eb2[g], dacc = 0.f;
#pragma unroll 5
    for (int l = 0; l < E1; ++l) {
        float2 x = hv[l];
        float w = ew2[l * GD + g];
        acc = fmaf(x.x, w, acc);
        dacc = fmaf(x.y, w, dacc);
    }
    float G = ftanh(acc);
    float dv = (1.f - G * G) * dacc;

    float2* f2 = (float2*)g_tab4;
    long e = ti * GD + g;
    f2[2 * e] = make_float2(G, dv);
    if (i > 0) f2[2 * (e - GD) + 1] = make_float2(G, dv);
}

// ---------------- table stage 3: fp16 packed table ----------------
__global__ __launch_bounds__(256) void k_table_h16() {
    long idx = (long)blockIdx.x * 256 + threadIdx.x;
    if (idx >= (long)NTYPES * NK * HCH) return;
    int g = idx % HCH;
    long ti = idx / HCH;
    _Float16* dst = h_tab + idx * 4;
    if (g >= GD) {
        dst[0] = (_Float16)0.f; dst[1] = (_Float16)0.f;
        dst[2] = (_Float16)0.f; dst[3] = (_Float16)0.f;
        return;
    }
    float4 r = g_tab4[ti * GD + g];     // (G_i, dv_i, G_{i+1}, dv_{i+1})
    dst[0] = (_Float16)r.x;
    dst[1] = (_Float16)(r.z - r.x);     // dG (avoids fp16 cancellation on d00 term)
    dst[2] = (_Float16)r.y;
    dst[3] = (_Float16)r.w;
}

__device__ __forceinline__ int hermite6(float s,
    float& c01, float& c10, float& c11,
    float& d00, float& d10, float& d11)
{
    float x = (s - S_MIN) * S_INVH;
    x = fminf(fmaxf(x, 0.f), (float)(NK - 1) - 1e-3f);
    int i = (int)x;
    float u = x - (float)i;
    float um = 1.f - u;
    c01 = u * u * (3.f - 2.f * u);
    c10 = S_H * u * um * um;
    c11 = S_H * u * u * (u - 1.f);
    d00 = (6.f * u * u - 6.f * u) * S_INVH;
    d10 = fmaf(3.f * u, u, fmaf(-4.f, u, 1.f));
    d11 = fmaf(3.f * u, u, -2.f * u);
    return i;
}

// ---------------- K1: LDS-precomputed basis; lane = channel-pair ----------------
__global__ __launch_bounds__(256) void k1_emb(
    const float* __restrict__ Ri,
    unsigned short* __restrict__ drb, float* __restrict__ xa_ws)
{
    __shared__ float4 a4s[JN];
    __shared__ uint2 cpak[JN];
    __shared__ int rowoff[JN];
    __shared__ float xar[4 * 400];
    __shared__ float xas[400];

    int tid = threadIdx.x;
    int lane = tid & 63;
    int w = tid >> 6;
    int n = blockIdx.x;

    if (tid < JN) {
        float4 a = ((const float4*)Ri)[(long)n * JN + tid];
        a4s[tid] = a;
        float c01, c10, c11, d00, d10, d11;
        int ik = hermite6(a.x, c01, c10, c11, d00, d10, d11);
        rowoff[tid] = ((tid / MAXNB) * NK + ik) * (HCH / 2);
        h16x2 cP; cP[0] = (_Float16)1.f;  cP[1] = (_Float16)c01;
        h16x2 cQ; cQ[0] = (_Float16)c10;  cQ[1] = (_Float16)c11;
        cpak[tid] = make_uint2(h2u(cP), h2u(cQ));
    }
    __syncthreads();

    float xe0 = 0.f, xe1 = 0.f, xe2 = 0.f, xe3 = 0.f;
    float xo0 = 0.f, xo1 = 0.f, xo2 = 0.f, xo3 = 0.f;

#pragma unroll 4
    for (int ii = 0; ii < 50; ++ii) {
        int j = w * 50 + ii;
        uint2 cc = cpak[j];
        const uint4* row4 = (const uint4*)h_tab + rowoff[j];
        if (lane < 50) {
            uint4 v = row4[lane];
            float4 a = a4s[j];
            float Ge = FDOT2(as_h2(v.y), as_h2(cc.y), FDOT2(as_h2(v.x), as_h2(cc.x), 0.f));
            float Go = FDOT2(as_h2(v.w), as_h2(cc.y), FDOT2(as_h2(v.z), as_h2(cc.x), 0.f));
            xe0 = fmaf(a.x, Ge, xe0); xe1 = fmaf(a.y, Ge, xe1);
            xe2 = fmaf(a.z, Ge, xe2); xe3 = fmaf(a.w, Ge, xe3);
            xo0 = fmaf(a.x, Go, xo0); xo1 = fmaf(a.y, Go, xo1);
            xo2 = fmaf(a.z, Go, xo2); xo3 = fmaf(a.w, Go, xo3);
        }
    }

    float* xw = xar + w * 400;
    if (lane < 50) {
        *(float2*)&xw[0 * GD + 2 * lane] = make_float2(xe0, xo0);
        *(float2*)&xw[1 * GD + 2 * lane] = make_float2(xe1, xo1);
        *(float2*)&xw[2 * GD + 2 * lane] = make_float2(xe2, xo2);
        *(float2*)&xw[3 * GD + 2 * lane] = make_float2(xe3, xo3);
    }
    __syncthreads();

    for (int i = tid; i < 400; i += 256) {
        float v = (xar[i] + xar[400 + i] + xar[800 + i] + xar[1200 + i]) * INV200;
        xas[i] = v;
        xa_ws[(long)n * 400 + i] = v;
    }
    __syncthreads();

    for (int i = tid; i < DD; i += 256) {
        int gg = i / M2D, m = i % M2D;
        float v = 0.f;
#pragma unroll
        for (int c = 0; c < 4; ++c) v = fmaf(xas[c * GD + gg], xas[c * GD + m], v);
        drb[(long)n * DD + i] = f2b(v);
    }
}

// ---------------- MFMA bf16 GEMM: C = act(A @ BT^T + bias) ----------------
// mode: 0 = none, 1 = tanh, 2 = v *= (1 - x^2) with x = X[row][col] (dh0g path).
__global__ __launch_bounds__(256) void mgemm(
    const unsigned short* __restrict__ Ab, const unsigned short* __restrict__ BTb,
    const float* __restrict__ biasb, float* __restrict__ Cb, unsigned short* __restrict__ Cbf,
    const float* __restrict__ Xb,
    int M, int N, int K, int Npad,
    long sA, long sBT, long sBias, long sC, long sCbf, long sX, int mode)
{
    int t = blockIdx.z;
    const unsigned short* A = Ab + (long)t * sA;
    const unsigned short* BT = BTb + (long)t * sBT;
    const float* bias = biasb ? biasb + (long)t * sBias : nullptr;
    float* C = Cb ? Cb + (long)t * sC : nullptr;
    unsigned short* Cb16 = Cbf ? Cbf + (long)t * sCbf : nullptr;
    const float* X = Xb ? Xb + (long)t * sX : nullptr;

    __shared__ __align__(16) unsigned short As[64 * 72];
    __shared__ __align__(16) unsigned short Bs[64 * 72];

    int tid = threadIdx.x;
    int m0 = blockIdx.x * 64;
    int n0 = blockIdx.y * 64;

    int lane = tid & 63;
    int w = tid >> 6;
    int wm = (w & 1) * 32;
    int wn = (w >> 1) * 32;
    int fm = lane & 15;
    int q = lane >> 4;

    f32x4 acc[2][2] = {};

    int sr = tid >> 2;
    int sc = tid & 3;

    const unsigned short* Ar = A + (long)(m0 + sr) * K + sc * 8;
    const unsigned short* Br = BT + (long)(n0 + sr) * K + sc * 8;
    unsigned short* Asw = As + sr * 72 + sc * 8;
    unsigned short* Bsw = Bs + sr * 72 + sc * 8;

    for (int k0 = 0; k0 < K; k0 += 64) {
        uint4 av0 = *(const uint4*)(Ar + k0);
        uint4 av1 = *(const uint4*)(Ar + k0 + 32);
        uint4 bv0 = *(const uint4*)(Br + k0);
        uint4 bv1 = *(const uint4*)(Br + k0 + 32);
        __syncthreads();
        *(uint4*)(Asw) = av0;
        *(uint4*)(Asw + 32) = av1;
        *(uint4*)(Bsw) = bv0;
        *(uint4*)(Bsw + 32) = bv1;
        __syncthreads();
#pragma unroll
        for (int kk = 0; kk < 64; kk += 32) {
            bf16x8 af0 = *(const bf16x8*)(As + (wm + fm) * 72 + kk + q * 8);
            bf16x8 af1 = *(const bf16x8*)(As + (wm + 16 + fm) * 72 + kk + q * 8);
            bf16x8 bg0 = *(const bf16x8*)(Bs + (wn + fm) * 72 + kk + q * 8);
            bf16x8 bg1 = *(const bf16x8*)(Bs + (wn + 16 + fm) * 72 + kk + q * 8);
            acc[0][0] = __builtin_amdgcn_mfma_f32_16x16x32_bf16(af0, bg0, acc[0][0], 0, 0, 0);
            acc[0][1] = __builtin_amdgcn_mfma_f32_16x16x32_bf16(af0, bg1, acc[0][1], 0, 0, 0);
            acc[1][0] = __builtin_amdgcn_mfma_f32_16x16x32_bf16(af1, bg0, acc[1][0], 0, 0, 0);
            acc[1][1] = __builtin_amdgcn_mfma_f32_16x16x32_bf16(af1, bg1, acc[1][1], 0, 0, 0);
        }
    }

    // C/D layout: col = lane&15, row = q*4 + reg
#pragma unroll
    for (int i = 0; i < 2; ++i) {
#pragma unroll
        for (int j = 0; j < 2; ++j) {
            int col = n0 + wn + j * 16 + fm;
            int rb = m0 + wm + i * 16 + q * 4;
            bool ok = col < N;
            float bv = (bias && ok) ? bias[col] : 0.f;
#pragma unroll
            for (int r = 0; r < 4; ++r) {
                float v = acc[i][j][r] + bv;
                if (mode == 1) {
                    v = ftanh(v);
                } else if (mode == 2 && ok) {
                    float x = X[(long)(rb + r) * N + col];
                    v *= (1.f - x * x);
                }
                if (ok && C) C[(long)(rb + r) * N + col] = v;
                if (Cb16) Cb16[(long)(rb + r) * Npad + col] = ok ? f2b(v) : (unsigned short)0;
            }
        }
    }
}

// ---------------- K3a (lite): per-atom Ei + Etot + u1 (bf16, K zero-padded) --------
__global__ __launch_bounds__(256) void k3a(
    const float* __restrict__ fh1, const float* __restrict__ fw2,
    const float* __restrict__ fb2,
    float* __restrict__ out, unsigned short* __restrict__ u1b)
{
    int n = blockIdx.x;
    int t = n / NA;
    int tid = threadIdx.x;
    __shared__ float red[256];

    float p = 0.f, u1 = 0.f;
    if (tid < FHD) {
        float h1v = fh1[(long)n * FHD + tid];
        float w2v = fw2[t * FHD + tid];
        p = h1v * w2v;
        u1 = w2v * (1.f - h1v * h1v);
    }
    u1b[(long)n * 256 + tid] = (tid < FHD) ? f2b(u1) : (unsigned short)0;
    red[tid] = p;
    __syncthreads();
    for (int off = 128; off > 0; off >>= 1) {
        if (tid < off) red[tid] += red[tid + off];
        __syncthreads();
    }
    if (tid == 0) {
        float e = red[0] + fb2[t];
        out[OUT_EI + n] = e;
        atomicAdd(out, e);
    }
}

// ---------------- K3b: per-atom P, g-major float4 [n][g][c] ----------------
__global__ __launch_bounds__(256) void k3b(
    const float* __restrict__ Q, const float* __restrict__ xa, float* __restrict__ P4)
{
    int n = blockIdx.x;
    int tid = threadIdx.x;
    __shared__ float qs[DD];
    __shared__ float xs[400];
    for (int i = tid; i < DD; i += 256) qs[i] = Q[(long)n * DD + i];
    for (int i = tid; i < 400; i += 256) xs[i] = xa[(long)n * 400 + i];
    __syncthreads();
    for (int i = tid; i < 400; i += 256) {
        int c = i / GD, g = i % GD;
        float acc = 0.f;
        for (int m = 0; m < M2D; ++m) acc = fmaf(qs[g * M2D + m], xs[c * GD + m], acc);
        if (g < M2D) {
            for (int g2 = 0; g2 < GD; ++g2) acc = fmaf(qs[g2 * M2D + g], xs[c * GD + g2], acc);
        }
        P4[((long)n * GD + g) * 4 + c] = acc * INV200;
    }
}

// ---------------- K4 tail: dEdx + scatter + virial for one item (LDS inputs) -------
__device__ __forceinline__ void k4_tail(
    int n, int j, float4 a,
    float M10, float M11, float M12, float M13,
    float M20, float M21, float M22, float M23,
    const float* __restrict__ dfs, const float* __restrict__ im_s,
    const int* __restrict__ ln_s, float* __restrict__ out, int ql,
    float& f0, float& f1, float& f2v,
    float& v00, float& v01, float& v02, float& v11, float& v12, float& v22)
{
    float ds = a.x * M20 + a.y * M21 + a.z * M22 + a.w * M23;
    float dEda0 = M10 + ds, dEda1 = M11, dEda2 = M12, dEda3 = M13;

    if (ql < 3) {
        float w0 = dfs[j * 12 + ql];
        float w1 = dfs[j * 12 + 3 + ql];
        float w2 = dfs[j * 12 + 6 + ql];
        float w3 = dfs[j * 12 + 9 + ql];
        float dEdx = dEda0 * w0 + dEda1 * w1 + dEda2 * w2 + dEda3 * w3;

        // self-force: accumulated for ALL items (mask applies to scatter only)
        if (ql == 0) f0 += dEdx;
        else if (ql == 1) f1 += dEdx;
        else f2v += dEdx;

        int ln = ln_s[j];
        if (ln > 0) {
            int ii2 = ln - 1;
            if (ii2 > NATOMS - 1) ii2 = NATOMS - 1;
            atomicAdd(&out[OUT_F + ii2 * 3 + ql], dEdx);
            float im0 = im_s[j * 3];
            float im1 = im_s[j * 3 + 1];
            float im2 = im_s[j * 3 + 2];
            if (ql == 0) {
                v00 += im0 * dEdx;
            } else if (ql == 1) {
                v01 += im0 * dEdx; v11 += im1 * dEdx;
            } else {
                v02 += im0 * dEdx; v12 += im1 * dEdx; v22 += im2 * dEdx;
            }
        }
    }
}

// ---------------- K4: quad-per-item, fp16 table + fdot2, FENCED burst-13 ----------
// R11 lesson: (256,6) capped VGPR at 85 -> r[13] spilled to scratch (1GB HBM traffic,
// 360us). REVERTED to (256,4) (needs >=88 VGPR headroom for the 52-reg burst).
// NEW: tail inputs (dfeat/ImageDR/list_neigh, all 200 items) staged into LDS at
// block start via coalesced float4 streams -- removes ~23 scattered lane-requests
// per item from the TA path (79 -> ~56, the modeled k4 bottleneck) and replaces
// per-pass global tail loads with LDS reads (no added live registers, LDS 5->18KB).
__global__ __launch_bounds__(256, 4) void k4(
    const float* __restrict__ Ri, const float* __restrict__ dfeat,
    const float* __restrict__ ImageDR, const int* __restrict__ list_neigh,
    const float4* __restrict__ P4ws, float* __restrict__ out)
{
    __shared__ float4 a4s[JN];
    __shared__ float4 P4s[HCH];
    __shared__ float4 df4[JN * 3];   // dfeat [j][12] = 3 float4/item
    __shared__ float im_s[JN * 3];
    __shared__ int ln_s[JN];
    __shared__ float fred[4][3];
    __shared__ float vred[4][6];
    __shared__ float vacc[6];

    int tid = threadIdx.x;
    int lane = tid & 63;
    int w = tid >> 6;
    int n = blockIdx.x;

    if (tid < JN) a4s[tid] = ntload4(&((const float4*)Ri)[(long)n * JN + tid]);
    if (tid < HCH)
        P4s[tid] = (tid < GD) ? ntload4(&P4ws[(long)n * GD + tid])
                              : make_float4(0.f, 0.f, 0.f, 0.f);
    // stage dfeat: 600 float4, coalesced
    {
        const float4* dfp = (const float4*)(dfeat + (long)n * JN * 12);
        for (int i = tid; i < JN * 3; i += 256) df4[i] = ntload4(&dfp[i]);
    }
    // stage ImageDR: 150 float4
    {
        const float4* imp = (const float4*)(ImageDR + (long)n * JN * 3);
        if (tid < (JN * 3) / 4) ((float4*)im_s)[tid] = ntload4(&imp[tid]);
    }
    // stage list_neigh: 50 int4
    {
        const int4* lnp = (const int4*)(list_neigh + (long)n * JN);
        if (tid < JN / 4) ((int4*)ln_s)[tid] = lnp[tid];
    }
    __syncthreads();

    int ql = lane & 3;
    int qid = w * 16 + (lane >> 2);   // block-wide quad id: 0..63

    float f0 = 0.f, f1 = 0.f, f2v = 0.f;
    float v00 = 0.f, v01 = 0.f, v02 = 0.f, v11 = 0.f, v12 = 0.f, v22 = 0.f;

    for (int pass = 0; pass < 4; ++pass) {
        int j;
        if (pass < 3) {
            j = pass * 64 + qid;          // 0..191
        } else {
            if (qid & 7) break;           // 8 quads spread over the 4 waves
            j = 192 + (qid >> 3);         // 192..199
        }

        float4 a = a4s[j];
        float c01, c10, c11, d00, d10, d11;
        int ik = hermite6(a.x, c01, c10, c11, d00, d10, d11);
        const uint4* row4 = (const uint4*)h_tab + (long)((j / MAXNB) * NK + ik) * (HCH / 2);

        h16x2 cP; cP[0] = (_Float16)1.f;   cP[1] = (_Float16)c01;
        h16x2 cQ; cQ[0] = (_Float16)c10;   cQ[1] = (_Float16)c11;
        h16x2 cR; cR[0] = (_Float16)0.f;   cR[1] = (_Float16)(-d00);
        h16x2 cS; cS[0] = (_Float16)d10;   cS[1] = (_Float16)d11;

        float M10 = 0.f, M11 = 0.f, M12 = 0.f, M13 = 0.f;
        float M20 = 0.f, M21 = 0.f, M22 = 0.f, M23 = 0.f;

        // ---- fenced burst: issue all 13 row loads before ANY compute ----
        uint4 r[13];
#pragma unroll
        for (int i2 = 0; i2 < 13; ++i2) r[i2] = row4[4 * i2 + ql];
        __builtin_amdgcn_sched_barrier(0);

#pragma unroll
        for (int i2 = 0; i2 < 13; ++i2) {
            int ca = 8 * i2 + 2 * ql;
            float4 pa = P4s[ca];
            float4 pb = P4s[ca + 1];
            float G1 = FDOT2(as_h2(r[i2].y), cQ, FDOT2(as_h2(r[i2].x), cP, 0.f));
            float D1 = FDOT2(as_h2(r[i2].y), cS, FDOT2(as_h2(r[i2].x), cR, 0.f));
            M10 = fmaf(pa.x, G1, M10); M11 = fmaf(pa.y, G1, M11);
            M12 = fmaf(pa.z, G1, M12); M13 = fmaf(pa.w, G1, M13);
            M20 = fmaf(pa.x, D1, M20); M21 = fmaf(pa.y, D1, M21);
            M22 = fmaf(pa.z, D1, M22); M23 = fmaf(pa.w, D1, M23);
            float G2 = FDOT2(as_h2(r[i2].w), cQ, FDOT2(as_h2(r[i2].z), cP, 0.f));
            float D2 = FDOT2(as_h2(r[i2].w), cS, FDOT2(as_h2(r[i2].z), cR, 0.f));
            M10 = fmaf(pb.x, G2, M10); M11 = fmaf(pb.y, G2, M11);
            M12 = fmaf(pb.z, G2, M12); M13 = fmaf(pb.w, G2, M13);
            M20 = fmaf(pb.x, D2, M20); M21 = fmaf(pb.y, D2, M21);
            M22 = fmaf(pb.z, D2, M22); M23 = fmaf(pb.w, D2, M23);
        }
        __builtin_amdgcn_sched_barrier(0);

        // intra-quad butterfly: all 4 lanes end with the full channel sums
#pragma unroll
        for (int mask = 1; mask <= 2; mask <<= 1) {
            M10 += __shfl_xor(M10, mask); M11 += __shfl_xor(M11, mask);
            M12 += __shfl_xor(M12, mask); M13 += __shfl_xor(M13, mask);
            M20 += __shfl_xor(M20, mask); M21 += __shfl_xor(M21, mask);
            M22 += __shfl_xor(M22, mask); M23 += __shfl_xor(M23, mask);
        }

        k4_tail(n, j, a, M10, M11, M12, M13, M20, M21, M22, M23,
                (const float*)df4, im_s, ln_s, out, ql, f0, f1, f2v,
                v00, v01, v02, v11, v12, v22);
    }

    // wave butterfly over self-force + virial partials (roles distributed per-lane;
    // the sum over all lanes recovers each slot's total)
#pragma unroll
    for (int mask = 32; mask > 0; mask >>= 1) {
        f0 += __shfl_xor(f0, mask);
        f1 += __shfl_xor(f1, mask);
        f2v += __shfl_xor(f2v, mask);
        v00 += __shfl_xor(v00, mask);
        v01 += __shfl_xor(v01, mask);
        v02 += __shfl_xor(v02, mask);
        v11 += __shfl_xor(v11, mask);
        v12 += __shfl_xor(v12, mask);
        v22 += __shfl_xor(v22, mask);
    }
    if (lane == 0) {
        fred[w][0] = f0; fred[w][1] = f1; fred[w][2] = f2v;
        vred[w][0] = v00; vred[w][1] = v01; vred[w][2] = v02;
        vred[w][3] = v11; vred[w][4] = v12; vred[w][5] = v22;
    }
    __syncthreads();
    if (tid < 3) {
        float s = fred[0][tid] + fred[1][tid] + fred[2][tid] + fred[3][tid];
        atomicAdd(&out[OUT_F + n * 3 + tid], -s);
    }
    if (tid < 6) {
        vacc[tid] = vred[0][tid] + vred[1][tid] + vred[2][tid] + vred[3][tid];
    }
    __syncthreads();
    if (tid < 9) {
        const int vmap[9] = {0, 1, 2, 1, 3, 4, 2, 4, 5};
        atomicAdd(&out[OUT_V + tid], vacc[vmap[tid]]);
    }
}

extern "C" void kernel_launch(void* const* d_in, const int* in_sizes, int n_in,
                              void* d_out, int out_size, void* d_ws, size_t ws_size,
                              hipStream_t stream) {
    const float* Ri = (const float*)d_in[0];
    const float* dfeat = (const float*)d_in[1];
    const float* ImageDR = (const float*)d_in[2];
    const float* tv = (const float*)d_in[3];
    const float* ew0 = (const float*)d_in[4];
    const float* eb0 = (const float*)d_in[5];
    const float* ew1 = (const float*)d_in[6];
    const float* eb1 = (const float*)d_in[7];
    const float* ew2 = (const float*)d_in[8];
    const float* eb2 = (const float*)d_in[9];
    const float* fw0 = (const float*)d_in[10];
    const float* fb0 = (const float*)d_in[11];
    const float* fw1 = (const float*)d_in[12];
    const float* fb1 = (const float*)d_in[13];
    const float* fw2 = (const float*)d_in[14];
    const float* fb2 = (const float*)d_in[15];
    const int* list_neigh = (const int*)d_in[16];

    float* out = (float*)d_out;
    float* ws = (float*)d_ws;
    float* Q = ws + WS_Q;
    unsigned short* fw1Nb = (unsigned short*)(ws + WS_FW1NB);
    unsigned short* drb = (unsigned short*)(ws + WS_DRB);
    unsigned short* u1b = (unsigned short*)(ws + WS_U1B);
    float* xa = ws + WS_XA;
    float* P = ws + WS_P;
    float* fh0 = ws + WS_FH0;
    float* fh1 = ws + WS_FH1;
    unsigned short* dh0gb = (unsigned short*)(ws + WS_DH0GB);
    unsigned short* fh0b = (unsigned short*)(ws + WS_FH0B);
    unsigned short* fw0Tb = (unsigned short*)(ws + WS_FW0TB);
    unsigned short* fw0b = (unsigned short*)(ws + WS_FW0B);
    unsigned short* fw1Tb = (unsigned short*)(ws + WS_FW1TB);

    hipMemsetAsync(d_out, 0, (size_t)out_size * sizeof(float), stream);

    k_setup<<<(NTYPES * DD * 256 + 255) / 256, 256, 0, stream>>>(
        fw0, fw1, fw0Tb, fw0b, fw1Tb, fw1Nb);
    k_table_h<<<(NTYPES * NK + 255) / 256, 256, 0, stream>>>(ew0, eb0, ew1, eb1, tv);
    k_table_g<<<(NTYPES * NK * GD + 255) / 256, 256, 0, stream>>>(ew2, eb2);
    k_table_h16<<<(NTYPES * NK * HCH + 255) / 256, 256, 0, stream>>>();

    k1_emb<<<NATOMS, 256, 0, stream>>>(Ri, drb, xa);

    // fh0 = tanh(dr @ fw0 + fb0)  [+ bf16 copy for next GEMM]
    mgemm<<<dim3(32, 4, 2), 256, 0, stream>>>(
        drb, fw0Tb, fb0, fh0, fh0b, nullptr,
        2048, 240, 1600, 256,
        2048L * 1600, 256L * 1600, 240L, 2048L * 240, 2048L * 256, 0L, 1);
    // fh1 = tanh(fh0 @ fw1 + fb1)
    mgemm<<<dim3(32, 4, 2), 256, 0, stream>>>(
        fh0b, fw1Tb, fb1, fh1, nullptr, nullptr,
        2048, 240, 256, 0,
        2048L * 256, 256L * 256, 240L, 2048L * 240, 0L, 0L, 1);

    // Ei/Etot + u1 (elementwise)
    k3a<<<NATOMS, 256, 0, stream>>>(fh1, fw2, fb2, out, u1b);

    // dh0g = (u1 @ fw1^T) * (1 - fh0^2)  -> bf16 dh0gb (K zero-padded)
    mgemm<<<dim3(32, 4, 2), 256, 0, stream>>>(
        u1b, fw1Nb, nullptr, nullptr, dh0gb, fh0,
        2048, 240, 256, 256,
        2048L * 256, 256L * 256, 0L, 0L, 2048L * 256, 2048L * 240, 2);

    // Q = dh0g @ fw0^T
    mgemm<<<dim3(32, 25, 2), 256, 0, stream>>>(
        dh0gb, fw0b, nullptr, Q, nullptr, nullptr,
        2048, 1600, 256, 0,
        2048L * 256, 1600L * 256, 0L, 2048L * 1600, 0L, 0L, 0);

    k3b<<<NATOMS, 256, 0, stream>>>(Q, xa, P);

    k4<<<NATOMS, 256, 0, stream>>>(Ri, dfeat, ImageDR, list_neigh,
        (const float4*)P, out);
}